// Round 1
// baseline (1136.495 us; speedup 1.0000x reference)
//
#include <hip/hip_runtime.h>
#include <hip/hip_bf16.h>
#include <math.h>

typedef __bf16 bf16_t;
typedef __bf16 bf16x8 __attribute__((ext_vector_type(8)));
typedef __bf16 bf16x4v __attribute__((ext_vector_type(4)));
typedef float  f32x4  __attribute__((ext_vector_type(4)));

constexpr int CB = 4, CS = 2048, CH = 2048, CNH = 16, CHD = 128;
constexpr int CM = CB * CS;  // 8192 rows of x
constexpr float CSCALE = 0.08838834764831845f;  // 128^-0.5
constexpr float CL2E   = 1.4426950408889634f;

// async global->LDS, 16B per lane. LDS dest is wave-uniform base (+lane*16 by HW).
__device__ __forceinline__ void g2l16(const void* g, void* l) {
  __builtin_amdgcn_global_load_lds(
      (const __attribute__((address_space(1))) void*)g,
      (__attribute__((address_space(3))) void*)l, 16, 0, 0);
}

// ---------------- f32 -> bf16 conversion (vectorized) ----------------
__global__ __launch_bounds__(256) void cvt_kernel(const float* __restrict__ in,
                                                  bf16_t* __restrict__ out, int n4) {
  int i = blockIdx.x * 256 + threadIdx.x;
  if (i >= n4) return;
  float4 v = reinterpret_cast<const float4*>(in)[i];
  bf16x4v o = {(bf16_t)v.x, (bf16_t)v.y, (bf16_t)v.z, (bf16_t)v.w};
  reinterpret_cast<bf16x4v*>(out)[i] = o;
}

// ---------------- GEMM core: C(128x128) = A(MxK) * Bm(NxK)^T, bf16, m97-style ----------------
__device__ __forceinline__ void gemm_core(const bf16_t* __restrict__ A,
                                          const bf16_t* __restrict__ Bm,
                                          bf16_t* As, bf16_t* Bs,
                                          int row0, int col0, int K,
                                          f32x4 (&acc)[4][4]) {
  const int tid = threadIdx.x;
  const int lane = tid & 63;
  const int w = tid >> 6;
  const int wr = (w >> 1) * 64;
  const int wc = (w & 1) * 64;
  for (int kt = 0; kt < K; kt += 32) {
    __syncthreads();
    // stage A,B tiles [128][32] bf16 = 8KB each. 512 chunks of 16B per tile.
#pragma unroll
    for (int i = 0; i < 2; ++i) {
      const int c = i * 256 + w * 64 + lane;
      const int r = c >> 2, kc = c & 3;
      g2l16(A  + (size_t)(row0 + r) * K + kt + kc * 8, As + (size_t)(i * 256 + w * 64) * 8);
      g2l16(Bm + (size_t)(col0 + r) * K + kt + kc * 8, Bs + (size_t)(i * 256 + w * 64) * 8);
    }
    __syncthreads();
    bf16x8 af[4], bfr[4];
#pragma unroll
    for (int f = 0; f < 4; ++f) {
      af[f]  = *(const bf16x8*)(As + (wr + f * 16 + (lane & 15)) * 32 + (lane >> 4) * 8);
      bfr[f] = *(const bf16x8*)(Bs + (wc + f * 16 + (lane & 15)) * 32 + (lane >> 4) * 8);
    }
#pragma unroll
    for (int i = 0; i < 4; ++i)
#pragma unroll
      for (int j = 0; j < 4; ++j)
        acc[i][j] = __builtin_amdgcn_mfma_f32_16x16x32_bf16(af[i], bfr[j], acc[i][j], 0, 0, 0);
  }
}

// ---------------- QKV projection (grid.z selects Q/K/V) ----------------
__global__ __launch_bounds__(256) void qkv_gemm(const bf16_t* __restrict__ xb,
                                                const bf16_t* __restrict__ wqb,
                                                const bf16_t* __restrict__ wkb,
                                                const bf16_t* __restrict__ wvb,
                                                bf16_t* __restrict__ qraw,
                                                bf16_t* __restrict__ kraw,
                                                bf16_t* __restrict__ vt,
                                                float* __restrict__ vout) {
  __shared__ __align__(16) bf16_t As[128 * 32];
  __shared__ __align__(16) bf16_t Bs[128 * 32];
  const int z = blockIdx.z;
  const bf16_t* Bm = (z == 0) ? wqb : ((z == 1) ? wkb : wvb);
  const int row0 = blockIdx.x * 128, col0 = blockIdx.y * 128;
  f32x4 acc[4][4] = {};
  gemm_core(xb, Bm, As, Bs, row0, col0, CH, acc);
  const int lane = threadIdx.x & 63, w = threadIdx.x >> 6;
  const int wr = (w >> 1) * 64, wc = (w & 1) * 64;
#pragma unroll
  for (int i = 0; i < 4; ++i) {
#pragma unroll
    for (int j = 0; j < 4; ++j) {
#pragma unroll
      for (int r = 0; r < 4; ++r) {
        const int gr = row0 + wr + i * 16 + (lane >> 4) * 4 + r;  // (b,s) row
        const int gc = col0 + wc + j * 16 + (lane & 15);          // nh*128+hd col
        const float v = acc[i][j][r];
        const int b = gr >> 11, s = gr & (CS - 1);
        const int nh = gc >> 7, hd = gc & (CHD - 1);
        const size_t idx = ((size_t)(b * CNH + nh) * CS + s) * CHD + hd;
        if (z == 2) {
          vout[idx] = v;  // f32 v output (B,NH,S,HD)
          vt[((size_t)(b * CNH + nh) * CHD + hd) * CS + s] = (bf16_t)v;  // V^T bf16
        } else {
          (z == 0 ? qraw : kraw)[idx] = (bf16_t)v;
        }
      }
    }
  }
}

// ---------------- output projection y = ob * Wo^T ----------------
__global__ __launch_bounds__(256) void y_gemm(const bf16_t* __restrict__ ob,
                                              const bf16_t* __restrict__ wob,
                                              float* __restrict__ yout) {
  __shared__ __align__(16) bf16_t As[128 * 32];
  __shared__ __align__(16) bf16_t Bs[128 * 32];
  const int row0 = blockIdx.x * 128, col0 = blockIdx.y * 128;
  f32x4 acc[4][4] = {};
  gemm_core(ob, wob, As, Bs, row0, col0, CH, acc);
  const int lane = threadIdx.x & 63, w = threadIdx.x >> 6;
  const int wr = (w >> 1) * 64, wc = (w & 1) * 64;
#pragma unroll
  for (int i = 0; i < 4; ++i)
#pragma unroll
    for (int j = 0; j < 4; ++j)
#pragma unroll
      for (int r = 0; r < 4; ++r) {
        const int gr = row0 + wr + i * 16 + (lane >> 4) * 4 + r;
        const int gc = col0 + wc + j * 16 + (lane & 15);
        yout[(size_t)gr * CH + gc] = acc[i][j][r];
      }
}

// ---------------- RoPE (in-place on bf16 Q/K, also writes f32 k output) ----------------
__global__ __launch_bounds__(256) void rope_kernel(bf16_t* __restrict__ qraw,
                                                   bf16_t* __restrict__ kraw,
                                                   const float* __restrict__ cosd,
                                                   const float* __restrict__ sind,
                                                   float* __restrict__ kout) {
  const int gid = blockIdx.x * 256 + threadIdx.x;  // over B*NH*S*64 pairs
  const int isK = blockIdx.y;
  bf16_t* p = isK ? kraw : qraw;
  const int row = gid >> 6, d = gid & 63;
  const int s = row & (CS - 1);
  const size_t base = (size_t)row * CHD;
  const float x1 = (float)p[base + d];
  const float x2 = (float)p[base + d + 64];
  const float c = cosd[s * CHD + d];
  const float sn = sind[s * CHD + d];
  const float o1 = x1 * c - x2 * sn;
  const float o2 = x2 * c + x1 * sn;
  p[base + d] = (bf16_t)o1;
  p[base + d + 64] = (bf16_t)o2;
  if (isK) {
    kout[base + d] = o1;
    kout[base + d + 64] = o2;
  }
}

// ---------------- flash attention ----------------
// grid: (S/64 q-tiles, B*NH). 4 waves/block, 16 q-rows per wave. KV tile = 128.
__global__ __launch_bounds__(256) void attn_kernel(const bf16_t* __restrict__ qb,
                                                   const bf16_t* __restrict__ kb,
                                                   const bf16_t* __restrict__ vt,
                                                   bf16_t* __restrict__ ob) {
  __shared__ __align__(16) bf16_t Ks[128 * 128];  // XOR-swizzled K tile
  __shared__ __align__(16) bf16_t Ps[64 * 128];   // XOR-swizzled P (wave-private rows)
  const int tid = threadIdx.x, lane = tid & 63, w = tid >> 6;
  const int qt = blockIdx.x, bh = blockIdx.y;
  const int b = bh >> 4, nh = bh & (CNH - 1);
  const size_t kvbase_g = (size_t)bh * CS * CHD;
  const int q0w = qt * 64 + w * 16;  // this wave's first q row

  // Q A-fragments held in registers: row = lane&15, k = (lane>>4)*8 (+kf*32)
  bf16x8 aq[4];
  {
    const bf16_t* qp = qb + kvbase_g + (size_t)(q0w + (lane & 15)) * CHD + (lane >> 4) * 8;
#pragma unroll
    for (int kf = 0; kf < 4; ++kf) aq[kf] = *(const bf16x8*)(qp + kf * 32);
  }

  float m_[4], l_[4];
  f32x4 o_[8];
  const f32x4 zf = {0.f, 0.f, 0.f, 0.f};
#pragma unroll
  for (int r = 0; r < 4; ++r) { m_[r] = -INFINITY; l_[r] = 0.f; }
#pragma unroll
  for (int h = 0; h < 8; ++h) o_[h] = zf;

  const int lastkt = (qt * 64 + 63) >> 7;
  for (int kt = 0; kt <= lastkt; ++kt) {
    __syncthreads();
    {  // stage K tile [128][128] bf16 = 32KB, pre-swizzled source (chunk ^= row&7)
      const bf16_t* kbase = kb + kvbase_g + (size_t)kt * 128 * CHD;
#pragma unroll
      for (int i = 0; i < 8; ++i) {
        const int c = i * 256 + w * 64 + lane;  // 16B chunk id, 16 chunks/row
        const int r = c >> 4, ck = c & 15;
        const int sck = ck ^ (r & 7);
        g2l16(kbase + (size_t)r * CHD + sck * 8, Ks + (size_t)(i * 256 + w * 64) * 8);
      }
    }
    __syncthreads();

    // QK^T: sf[cf] covers kv cols [cf*16, cf*16+16)
    f32x4 sf[8] = {};
#pragma unroll
    for (int kf = 0; kf < 4; ++kf) {
#pragma unroll
      for (int cf = 0; cf < 8; ++cf) {
        const int krow = cf * 16 + (lane & 15);
        const int lc = kf * 4 + (lane >> 4);
        bf16x8 bk = *(const bf16x8*)(Ks + krow * 128 + ((lc ^ (krow & 7)) << 3));
        sf[cf] = __builtin_amdgcn_mfma_f32_16x16x32_bf16(aq[kf], bk, sf[cf], 0, 0, 0);
      }
    }

    // scale + causal mask + row max
    const int kvb = kt * 128;
    float tmax[4];
#pragma unroll
    for (int r = 0; r < 4; ++r) tmax[r] = -INFINITY;
#pragma unroll
    for (int cf = 0; cf < 8; ++cf) {
      const int kv = kvb + cf * 16 + (lane & 15);
#pragma unroll
      for (int r = 0; r < 4; ++r) {
        const int qr = q0w + (lane >> 4) * 4 + r;
        const float xv = (kv <= qr) ? sf[cf][r] * CSCALE : -INFINITY;
        sf[cf][r] = xv;
        tmax[r] = fmaxf(tmax[r], xv);
      }
    }
#pragma unroll
    for (int off = 1; off < 16; off <<= 1)
#pragma unroll
      for (int r = 0; r < 4; ++r)
        tmax[r] = fmaxf(tmax[r], __shfl_xor(tmax[r], off, 64));

    float corr[4], psum[4];
#pragma unroll
    for (int r = 0; r < 4; ++r) {
      const float mn = fmaxf(m_[r], tmax[r]);
      corr[r] = exp2f((m_[r] - mn) * CL2E);
      m_[r] = mn;
      psum[r] = 0.f;
    }

    // P = exp(s - m), write to swizzled Ps (wave-private rows -> no barrier needed)
#pragma unroll
    for (int cf = 0; cf < 8; ++cf) {
#pragma unroll
      for (int r = 0; r < 4; ++r) {
        const float pv = exp2f((sf[cf][r] - m_[r]) * CL2E);
        psum[r] += pv;
        const int prow = w * 16 + (lane >> 4) * 4 + r;
        const int col = cf * 16 + (lane & 15);
        Ps[prow * 128 + (((col >> 3) ^ (prow & 7)) << 3) + (col & 7)] = (bf16_t)pv;
      }
    }
#pragma unroll
    for (int off = 1; off < 16; off <<= 1)
#pragma unroll
      for (int r = 0; r < 4; ++r)
        psum[r] += __shfl_xor(psum[r], off, 64);
#pragma unroll
    for (int r = 0; r < 4; ++r) l_[r] = l_[r] * corr[r] + psum[r];
#pragma unroll
    for (int h = 0; h < 8; ++h)
#pragma unroll
      for (int r = 0; r < 4; ++r) o_[h][r] *= corr[r];

    // PV: A = P (from swizzled Ps), B = V^T from global (contiguous along kv)
    const bf16_t* vbh = vt + (size_t)bh * CHD * CS;
#pragma unroll
    for (int kf = 0; kf < 4; ++kf) {
      const int prow = w * 16 + (lane & 15);
      const int lc = kf * 4 + (lane >> 4);
      bf16x8 ap = *(const bf16x8*)(Ps + prow * 128 + ((lc ^ (prow & 7)) << 3));
#pragma unroll
      for (int hf = 0; hf < 8; ++hf) {
        bf16x8 bv = *(const bf16x8*)(vbh + (size_t)(hf * 16 + (lane & 15)) * CS +
                                     kvb + kf * 32 + (lane >> 4) * 8);
        o_[hf] = __builtin_amdgcn_mfma_f32_16x16x32_bf16(ap, bv, o_[hf], 0, 0, 0);
      }
    }
  }

  // normalize + write ob in (B*S, H) layout for the y-GEMM
#pragma unroll
  for (int r = 0; r < 4; ++r) l_[r] = 1.0f / l_[r];
  const size_t obase = (size_t)b * CS * CH;
#pragma unroll
  for (int hf = 0; hf < 8; ++hf) {
#pragma unroll
    for (int r = 0; r < 4; ++r) {
      const int qr = q0w + (lane >> 4) * 4 + r;
      const int col = nh * CHD + hf * 16 + (lane & 15);
      ob[obase + (size_t)qr * CH + col] = (bf16_t)(o_[hf][r] * l_[r]);
    }
  }
}

extern "C" void kernel_launch(void* const* d_in, const int* in_sizes, int n_in,
                              void* d_out, int out_size, void* d_ws, size_t ws_size,
                              hipStream_t stream) {
  const float* x    = (const float*)d_in[0];
  const float* cosd = (const float*)d_in[1];
  const float* sind = (const float*)d_in[2];
  // d_in[3] = mask (causal, hardcoded)
  const float* Wq = (const float*)d_in[4];
  const float* Wk = (const float*)d_in[5];
  const float* Wv = (const float*)d_in[6];
  const float* Wo = (const float*)d_in[7];

  float* yout = (float*)d_out;
  float* kout = yout + (size_t)CM * CH;
  float* vout = kout + (size_t)CM * CH;

  char* ws = (char*)d_ws;
  size_t off = 0;
  auto wsalloc = [&](size_t bytes) {
    void* p = ws + off;
    off += (bytes + 255) & ~(size_t)255;
    return p;
  };
  bf16_t* xb   = (bf16_t*)wsalloc((size_t)CM * CH * 2);
  bf16_t* wqb  = (bf16_t*)wsalloc((size_t)CH * CH * 2);
  bf16_t* wkb  = (bf16_t*)wsalloc((size_t)CH * CH * 2);
  bf16_t* wvb  = (bf16_t*)wsalloc((size_t)CH * CH * 2);
  bf16_t* wob  = (bf16_t*)wsalloc((size_t)CH * CH * 2);
  bf16_t* qraw = (bf16_t*)wsalloc((size_t)CM * CH * 2);  // -> RoPE'd q (in-place)
  bf16_t* kraw = (bf16_t*)wsalloc((size_t)CM * CH * 2);  // -> RoPE'd k (in-place)
  bf16_t* vt   = (bf16_t*)wsalloc((size_t)CM * CH * 2);  // V^T [bh][hd][S]
  bf16_t* ob   = (bf16_t*)wsalloc((size_t)CM * CH * 2);  // attn out (B*S, H)

  cvt_kernel<<<CM * CH / 4 / 256, 256, 0, stream>>>(x, xb, CM * CH / 4);
  cvt_kernel<<<CH * CH / 4 / 256, 256, 0, stream>>>(Wq, wqb, CH * CH / 4);
  cvt_kernel<<<CH * CH / 4 / 256, 256, 0, stream>>>(Wk, wkb, CH * CH / 4);
  cvt_kernel<<<CH * CH / 4 / 256, 256, 0, stream>>>(Wv, wvb, CH * CH / 4);
  cvt_kernel<<<CH * CH / 4 / 256, 256, 0, stream>>>(Wo, wob, CH * CH / 4);

  qkv_gemm<<<dim3(CM / 128, CH / 128, 3), 256, 0, stream>>>(xb, wqb, wkb, wvb,
                                                            qraw, kraw, vt, vout);
  rope_kernel<<<dim3(CB * CNH * CS * 64 / 256, 2), 256, 0, stream>>>(qraw, kraw, cosd,
                                                                     sind, kout);
  attn_kernel<<<dim3(CS / 64, CB * CNH), 256, 0, stream>>>(qraw, kraw, vt, ob);
  y_gemm<<<dim3(CM / 128, CH / 128), 256, 0, stream>>>(ob, wob, yout);
}

// Round 2
// 742.000 us; speedup vs baseline: 1.5317x; 1.5317x over previous
//
#include <hip/hip_runtime.h>
#include <hip/hip_bf16.h>
#include <math.h>

typedef __bf16 bf16_t;
typedef __bf16 bf16x8 __attribute__((ext_vector_type(8)));
typedef __bf16 bf16x4v __attribute__((ext_vector_type(4)));
typedef float  f32x4  __attribute__((ext_vector_type(4)));

constexpr int CB = 4, CS = 2048, CH = 2048, CNH = 16, CHD = 128;
constexpr int CM = CB * CS;  // 8192 rows of x
constexpr float CSCALE = 0.08838834764831845f;  // 128^-0.5
constexpr float CL2E   = 1.4426950408889634f;

// async global->LDS, 16B per lane. LDS dest is wave-uniform base (+lane*16 by HW).
__device__ __forceinline__ void g2l16(const void* g, void* l) {
  __builtin_amdgcn_global_load_lds(
      (const __attribute__((address_space(1))) void*)g,
      (__attribute__((address_space(3))) void*)l, 16, 0, 0);
}

// ---------------- f32 -> bf16 conversion (vectorized) ----------------
__global__ __launch_bounds__(256) void cvt_kernel(const float* __restrict__ in,
                                                  bf16_t* __restrict__ out, int n4) {
  int i = blockIdx.x * 256 + threadIdx.x;
  if (i >= n4) return;
  float4 v = reinterpret_cast<const float4*>(in)[i];
  bf16x4v o = {(bf16_t)v.x, (bf16_t)v.y, (bf16_t)v.z, (bf16_t)v.w};
  reinterpret_cast<bf16x4v*>(out)[i] = o;
}

// ---------------- GEMM core: C(128x128) = A(MxK) * Bm(NxK)^T, bf16, m97-style ----------------
__device__ __forceinline__ void gemm_core(const bf16_t* __restrict__ A,
                                          const bf16_t* __restrict__ Bm,
                                          bf16_t* As, bf16_t* Bs,
                                          int row0, int col0, int K,
                                          f32x4 (&acc)[4][4]) {
  const int tid = threadIdx.x;
  const int lane = tid & 63;
  const int w = tid >> 6;
  const int wr = (w >> 1) * 64;
  const int wc = (w & 1) * 64;
  for (int kt = 0; kt < K; kt += 32) {
    __syncthreads();
    // stage A,B tiles [128][32] bf16 = 8KB each. 512 chunks of 16B per tile.
#pragma unroll
    for (int i = 0; i < 2; ++i) {
      const int c = i * 256 + w * 64 + lane;
      const int r = c >> 2, kc = c & 3;
      g2l16(A  + (size_t)(row0 + r) * K + kt + kc * 8, As + (size_t)(i * 256 + w * 64) * 8);
      g2l16(Bm + (size_t)(col0 + r) * K + kt + kc * 8, Bs + (size_t)(i * 256 + w * 64) * 8);
    }
    __syncthreads();
    bf16x8 af[4], bfr[4];
#pragma unroll
    for (int f = 0; f < 4; ++f) {
      af[f]  = *(const bf16x8*)(As + (wr + f * 16 + (lane & 15)) * 32 + (lane >> 4) * 8);
      bfr[f] = *(const bf16x8*)(Bs + (wc + f * 16 + (lane & 15)) * 32 + (lane >> 4) * 8);
    }
#pragma unroll
    for (int i = 0; i < 4; ++i)
#pragma unroll
      for (int j = 0; j < 4; ++j)
        acc[i][j] = __builtin_amdgcn_mfma_f32_16x16x32_bf16(af[i], bfr[j], acc[i][j], 0, 0, 0);
  }
}

// ---------------- QKV projection (grid.z selects Q/K/V) ----------------
__global__ __launch_bounds__(256) void qkv_gemm(const bf16_t* __restrict__ xb,
                                                const bf16_t* __restrict__ wqb,
                                                const bf16_t* __restrict__ wkb,
                                                const bf16_t* __restrict__ wvb,
                                                bf16_t* __restrict__ qraw,
                                                bf16_t* __restrict__ kraw,
                                                bf16_t* __restrict__ vt,
                                                float* __restrict__ vout) {
  __shared__ __align__(16) bf16_t As[128 * 32];
  __shared__ __align__(16) bf16_t Bs[128 * 32];
  const int z = blockIdx.z;
  const bf16_t* Bm = (z == 0) ? wqb : ((z == 1) ? wkb : wvb);
  const int row0 = blockIdx.x * 128, col0 = blockIdx.y * 128;
  f32x4 acc[4][4] = {};
  gemm_core(xb, Bm, As, Bs, row0, col0, CH, acc);
  const int lane = threadIdx.x & 63, w = threadIdx.x >> 6;
  const int wr = (w >> 1) * 64, wc = (w & 1) * 64;
#pragma unroll
  for (int i = 0; i < 4; ++i) {
#pragma unroll
    for (int j = 0; j < 4; ++j) {
      const int gr0 = row0 + wr + i * 16 + (lane >> 4) * 4;  // 4 consecutive (b,s) rows
      const int gc = col0 + wc + j * 16 + (lane & 15);       // nh*128+hd col
      const int b = gr0 >> 11, s0 = gr0 & (CS - 1);
      const int nh = gc >> 7, hd = gc & (CHD - 1);
      if (z == 2) {
#pragma unroll
        for (int r = 0; r < 4; ++r) {
          const size_t idx = ((size_t)(b * CNH + nh) * CS + s0 + r) * CHD + hd;
          vout[idx] = acc[i][j][r];  // f32 v output (B,NH,S,HD)
        }
        bf16x4v pv = {(bf16_t)acc[i][j][0], (bf16_t)acc[i][j][1],
                      (bf16_t)acc[i][j][2], (bf16_t)acc[i][j][3]};
        *(bf16x4v*)(vt + ((size_t)(b * CNH + nh) * CHD + hd) * CS + s0) = pv;  // V^T bf16
      } else {
        bf16_t* dst = (z == 0) ? qraw : kraw;
#pragma unroll
        for (int r = 0; r < 4; ++r) {
          const size_t idx = ((size_t)(b * CNH + nh) * CS + s0 + r) * CHD + hd;
          dst[idx] = (bf16_t)acc[i][j][r];
        }
      }
    }
  }
}

// ---------------- output projection y = ob * Wo^T ----------------
__global__ __launch_bounds__(256) void y_gemm(const bf16_t* __restrict__ ob,
                                              const bf16_t* __restrict__ wob,
                                              float* __restrict__ yout) {
  __shared__ __align__(16) bf16_t As[128 * 32];
  __shared__ __align__(16) bf16_t Bs[128 * 32];
  const int row0 = blockIdx.x * 128, col0 = blockIdx.y * 128;
  f32x4 acc[4][4] = {};
  gemm_core(ob, wob, As, Bs, row0, col0, CH, acc);
  const int lane = threadIdx.x & 63, w = threadIdx.x >> 6;
  const int wr = (w >> 1) * 64, wc = (w & 1) * 64;
#pragma unroll
  for (int i = 0; i < 4; ++i)
#pragma unroll
    for (int j = 0; j < 4; ++j)
#pragma unroll
      for (int r = 0; r < 4; ++r) {
        const int gr = row0 + wr + i * 16 + (lane >> 4) * 4 + r;
        const int gc = col0 + wc + j * 16 + (lane & 15);
        yout[(size_t)gr * CH + gc] = acc[i][j][r];
      }
}

// ---------------- RoPE (in-place on bf16 Q/K, also writes f32 k output) ----------------
__global__ __launch_bounds__(256) void rope_kernel(bf16_t* __restrict__ qraw,
                                                   bf16_t* __restrict__ kraw,
                                                   const float* __restrict__ cosd,
                                                   const float* __restrict__ sind,
                                                   float* __restrict__ kout) {
  const int gid = blockIdx.x * 256 + threadIdx.x;  // over B*NH*S*64 pairs
  const int isK = blockIdx.y;
  bf16_t* p = isK ? kraw : qraw;
  const int row = gid >> 6, d = gid & 63;
  const int s = row & (CS - 1);
  const size_t base = (size_t)row * CHD;
  const float x1 = (float)p[base + d];
  const float x2 = (float)p[base + d + 64];
  const float c = cosd[s * CHD + d];
  const float sn = sind[s * CHD + d];
  const float o1 = x1 * c - x2 * sn;
  const float o2 = x2 * c + x1 * sn;
  p[base + d] = (bf16_t)o1;
  p[base + d + 64] = (bf16_t)o2;
  if (isK) {
    kout[base + d] = o1;
    kout[base + d + 64] = o2;
  }
}

// ---------------- flash attention ----------------
// 1-D grid of 2048 blocks -> (qt, bh) via XCD swizzle + heavy-first qt.
// 4 waves/block, 16 q-rows per wave (QBLK=64). KVBLK=64, K & V double-buffered
// in LDS with async prefetch of tile t+1 issued before computing tile t.
__global__ __launch_bounds__(256) void attn_kernel(const bf16_t* __restrict__ qb,
                                                   const bf16_t* __restrict__ kb,
                                                   const bf16_t* __restrict__ vt,
                                                   bf16_t* __restrict__ ob) {
  __shared__ __align__(16) bf16_t Ks[2][64 * 128];   // [kv][hd], 16 chunks/row, XOR-swz
  __shared__ __align__(16) bf16_t Vs[2][128 * 64];   // [hd][kv], 8 chunks/row, XOR-swz
  __shared__ __align__(16) bf16_t Ps[4][16 * 64];    // per-wave [q][kv], 8 chunks/row, XOR-swz
  const int tid = threadIdx.x, lane = tid & 63, w = tid >> 6;

  // XCD-aware swizzle (2048 % 8 == 0 -> simple bijective form), heavy qt first.
  const int swz = (blockIdx.x & 7) * 256 + (blockIdx.x >> 3);
  const int bh = swz >> 5;
  const int qt = 31 - (swz & 31);

  const int b = bh >> 4, nh = bh & (CNH - 1);
  const size_t kvbase_g = (size_t)bh * CS * CHD;
  const bf16_t* vbh = vt + (size_t)bh * CHD * CS;
  const int q0w = qt * 64 + w * 16;  // this wave's first q row

  // Q A-fragments in registers: row = lane&15, k = (lane>>4)*8 (+kf*32)
  bf16x8 aq[4];
  {
    const bf16_t* qp = qb + kvbase_g + (size_t)(q0w + (lane & 15)) * CHD + (lane >> 4) * 8;
#pragma unroll
    for (int kf = 0; kf < 4; ++kf) aq[kf] = *(const bf16x8*)(qp + kf * 32);
  }

  float m_[4], l_[4];
  f32x4 o_[8];
  const f32x4 zf = {0.f, 0.f, 0.f, 0.f};
#pragma unroll
  for (int r = 0; r < 4; ++r) { m_[r] = -INFINITY; l_[r] = 0.f; }
#pragma unroll
  for (int h = 0; h < 8; ++h) o_[h] = zf;

  // stage K[64][128] (swizzled chunks, 1024 x 16B) + V^T[128][64] (1024 x 16B)
  auto stage = [&](int buf, int kt) {
    const bf16_t* kbase = kb + kvbase_g + (size_t)kt * 64 * CHD;
#pragma unroll
    for (int i = 0; i < 4; ++i) {
      const int c = i * 256 + w * 64 + lane;
      const int r = c >> 4, ck = c & 15;
      g2l16(kbase + (size_t)r * CHD + ((ck ^ (r & 7)) << 3),
            &Ks[buf][(size_t)(i * 256 + w * 64) * 8]);
    }
#pragma unroll
    for (int i = 0; i < 4; ++i) {
      const int c = i * 256 + w * 64 + lane;
      const int r = c >> 3, ck = c & 7;
      g2l16(vbh + (size_t)r * CS + kt * 64 + ((ck ^ (r & 7)) << 3),
            &Vs[buf][(size_t)(i * 256 + w * 64) * 8]);
    }
  };

  const int nt = qt + 1;
  stage(0, 0);
  __syncthreads();  // drains vmcnt before any LDS read
  int cur = 0;

  for (int kt = 0; kt < nt; ++kt) {
    if (kt + 1 < nt) stage(cur ^ 1, kt + 1);  // async prefetch into other buffer

    // QK^T: sf[cf] covers kv cols [cf*16, cf*16+16)
    f32x4 sf[4] = {};
#pragma unroll
    for (int kf = 0; kf < 4; ++kf) {
#pragma unroll
      for (int cf = 0; cf < 4; ++cf) {
        const int krow = cf * 16 + (lane & 15);
        const int lc = kf * 4 + (lane >> 4);
        bf16x8 bk = *(const bf16x8*)(&Ks[cur][krow * 128 + ((lc ^ (krow & 7)) << 3)]);
        sf[cf] = __builtin_amdgcn_mfma_f32_16x16x32_bf16(aq[kf], bk, sf[cf], 0, 0, 0);
      }
    }

    // scale + (diagonal-only) causal mask + row max
    const int kvb = kt * 64;
    const bool diag = (kt == nt - 1);
    float tmax[4];
#pragma unroll
    for (int r = 0; r < 4; ++r) tmax[r] = -INFINITY;
#pragma unroll
    for (int cf = 0; cf < 4; ++cf) {
      const int kv = kvb + cf * 16 + (lane & 15);
#pragma unroll
      for (int r = 0; r < 4; ++r) {
        const int qr = q0w + (lane >> 4) * 4 + r;
        float xv = sf[cf][r] * CSCALE;
        if (diag && kv > qr) xv = -INFINITY;
        sf[cf][r] = xv;
        tmax[r] = fmaxf(tmax[r], xv);
      }
    }
#pragma unroll
    for (int off = 1; off < 16; off <<= 1)
#pragma unroll
      for (int r = 0; r < 4; ++r)
        tmax[r] = fmaxf(tmax[r], __shfl_xor(tmax[r], off, 64));

    // defer-max (T13): only rescale when the running max grew by > 8
    bool need = false;
#pragma unroll
    for (int r = 0; r < 4; ++r) need |= (tmax[r] - m_[r]) > 8.0f;
    if (__any(need)) {
#pragma unroll
      for (int r = 0; r < 4; ++r) {
        const float mn = fmaxf(m_[r], tmax[r]);
        const float corr = exp2f((m_[r] - mn) * CL2E);
        m_[r] = mn;
        l_[r] *= corr;
#pragma unroll
        for (int h = 0; h < 8; ++h) o_[h][r] *= corr;
      }
    }

    // P = exp(s - m) -> swizzled per-wave Ps (no barrier needed)
    float psum[4] = {0.f, 0.f, 0.f, 0.f};
#pragma unroll
    for (int cf = 0; cf < 4; ++cf) {
#pragma unroll
      for (int r = 0; r < 4; ++r) {
        const float pv = exp2f((sf[cf][r] - m_[r]) * CL2E);
        psum[r] += pv;
        const int prow = (lane >> 4) * 4 + r;
        const int col = cf * 16 + (lane & 15);
        Ps[w][prow * 64 + (((col >> 3) ^ (prow & 7)) << 3) + (col & 7)] = (bf16_t)pv;
      }
    }
#pragma unroll
    for (int off = 1; off < 16; off <<= 1)
#pragma unroll
      for (int r = 0; r < 4; ++r)
        psum[r] += __shfl_xor(psum[r], off, 64);
#pragma unroll
    for (int r = 0; r < 4; ++r) l_[r] += psum[r];

    // PV: A = P (swizzled Ps), B = V^T tile from LDS
#pragma unroll
    for (int kf = 0; kf < 2; ++kf) {
      const int prow = lane & 15;
      const int lc = kf * 4 + (lane >> 4);
      bf16x8 ap = *(const bf16x8*)(&Ps[w][prow * 64 + ((lc ^ (prow & 7)) << 3)]);
#pragma unroll
      for (int hf = 0; hf < 8; ++hf) {
        const int vrow = hf * 16 + (lane & 15);
        bf16x8 bv = *(const bf16x8*)(&Vs[cur][vrow * 64 + ((lc ^ (vrow & 7)) << 3)]);
        o_[hf] = __builtin_amdgcn_mfma_f32_16x16x32_bf16(ap, bv, o_[hf], 0, 0, 0);
      }
    }

    __syncthreads();  // drains prefetch vmcnt + guards buffer swap
    cur ^= 1;
  }

  // normalize + write ob in (B*S, H) layout for the y-GEMM
#pragma unroll
  for (int r = 0; r < 4; ++r) l_[r] = 1.0f / l_[r];
  const size_t obase = (size_t)b * CS * CH;
#pragma unroll
  for (int hf = 0; hf < 8; ++hf) {
#pragma unroll
    for (int r = 0; r < 4; ++r) {
      const int qr = q0w + (lane >> 4) * 4 + r;
      const int col = nh * CHD + hf * 16 + (lane & 15);
      ob[obase + (size_t)qr * CH + col] = (bf16_t)(o_[hf][r] * l_[r]);
    }
  }
}

extern "C" void kernel_launch(void* const* d_in, const int* in_sizes, int n_in,
                              void* d_out, int out_size, void* d_ws, size_t ws_size,
                              hipStream_t stream) {
  const float* x    = (const float*)d_in[0];
  const float* cosd = (const float*)d_in[1];
  const float* sind = (const float*)d_in[2];
  // d_in[3] = mask (causal, hardcoded)
  const float* Wq = (const float*)d_in[4];
  const float* Wk = (const float*)d_in[5];
  const float* Wv = (const float*)d_in[6];
  const float* Wo = (const float*)d_in[7];

  float* yout = (float*)d_out;
  float* kout = yout + (size_t)CM * CH;
  float* vout = kout + (size_t)CM * CH;

  char* ws = (char*)d_ws;
  size_t off = 0;
  auto wsalloc = [&](size_t bytes) {
    void* p = ws + off;
    off += (bytes + 255) & ~(size_t)255;
    return p;
  };
  bf16_t* xb   = (bf16_t*)wsalloc((size_t)CM * CH * 2);
  bf16_t* wqb  = (bf16_t*)wsalloc((size_t)CH * CH * 2);
  bf16_t* wkb  = (bf16_t*)wsalloc((size_t)CH * CH * 2);
  bf16_t* wvb  = (bf16_t*)wsalloc((size_t)CH * CH * 2);
  bf16_t* wob  = (bf16_t*)wsalloc((size_t)CH * CH * 2);
  bf16_t* qraw = (bf16_t*)wsalloc((size_t)CM * CH * 2);  // -> RoPE'd q (in-place)
  bf16_t* kraw = (bf16_t*)wsalloc((size_t)CM * CH * 2);  // -> RoPE'd k (in-place)
  bf16_t* vt   = (bf16_t*)wsalloc((size_t)CM * CH * 2);  // V^T [bh][hd][S]
  bf16_t* ob   = (bf16_t*)wsalloc((size_t)CM * CH * 2);  // attn out (B*S, H)

  cvt_kernel<<<CM * CH / 4 / 256, 256, 0, stream>>>(x, xb, CM * CH / 4);
  cvt_kernel<<<CH * CH / 4 / 256, 256, 0, stream>>>(Wq, wqb, CH * CH / 4);
  cvt_kernel<<<CH * CH / 4 / 256, 256, 0, stream>>>(Wk, wkb, CH * CH / 4);
  cvt_kernel<<<CH * CH / 4 / 256, 256, 0, stream>>>(Wv, wvb, CH * CH / 4);
  cvt_kernel<<<CH * CH / 4 / 256, 256, 0, stream>>>(Wo, wob, CH * CH / 4);

  qkv_gemm<<<dim3(CM / 128, CH / 128, 3), 256, 0, stream>>>(xb, wqb, wkb, wvb,
                                                            qraw, kraw, vt, vout);
  rope_kernel<<<dim3(CB * CNH * CS * 64 / 256, 2), 256, 0, stream>>>(qraw, kraw, cosd,
                                                                     sind, kout);
  attn_kernel<<<CS / 64 * CB * CNH, 256, 0, stream>>>(qraw, kraw, vt, ob);
  y_gemm<<<dim3(CM / 128, CH / 128), 256, 0, stream>>>(ob, wob, yout);
}